// Round 10
// baseline (272.119 us; speedup 1.0000x reference)
//
#include <hip/hip_runtime.h>
#include <cstdint>
#include <cstddef>
#include <cmath>

typedef __attribute__((ext_vector_type(4))) float f32x4;
typedef __attribute__((ext_vector_type(8))) short bf16x8;

typedef const __attribute__((address_space(1))) void* gas_ptr;
typedef __attribute__((address_space(3))) void* las_ptr;

static __device__ __forceinline__ short f2bf(float f) {
    union { float f; uint32_t u; } v; v.f = f;
    uint32_t r = v.u + 0x7fffu + ((v.u >> 16) & 1u);
    return (short)(r >> 16);
}

// M padded: each batch gets 392 rows (388 real + 4 pad, zeros) so 8-elem
// m-chunks never straddle a batch boundary. M' = 64*392 = 25088 = 98*256.
constexpr int MP = 25088;

// ---------------- fp32 -> bf16 conversions ----------------
__global__ void cvt_f32_bf16(const float* __restrict__ src, short* __restrict__ dst, int n4) {
    int i = blockIdx.x * blockDim.x + threadIdx.x;
    const int stride = gridDim.x * blockDim.x;
    for (; i < n4; i += stride) {
        const float4 v = reinterpret_cast<const float4*>(src)[i];
        short4 o;
        o.x = f2bf(v.x); o.y = f2bf(v.y); o.z = f2bf(v.z); o.w = f2bf(v.w);
        reinterpret_cast<short4*>(dst)[i] = o;
    }
}

// x (64,388,768) f32 -> xb (64,392,768) bf16 with zero pad rows
__global__ void cvt_x_pad(const float* __restrict__ src, short* __restrict__ dst) {
    constexpr int N4 = MP * 768 / 4;
    int i = blockIdx.x * blockDim.x + threadIdx.x;
    const int stride = gridDim.x * blockDim.x;
    for (; i < N4; i += stride) {
        const int flat = i * 4;
        const int mp  = flat / 768;
        const int col = flat - mp * 768;
        const int b   = mp / 392;
        const int nn  = mp - b * 392;
        short4 o;
        if (nn < 388) {
            const float4 v = *reinterpret_cast<const float4*>(
                src + ((size_t)(b * 388 + nn) * 768 + col));
            o.x = f2bf(v.x); o.y = f2bf(v.y); o.z = f2bf(v.z); o.w = f2bf(v.w);
        } else {
            o.x = 0; o.y = 0; o.z = 0; o.w = 0;
        }
        reinterpret_cast<short4*>(dst)[i] = o;
    }
}

// ---------------- QKV GEMM, 256x256 8-wave 4-phase pipelined ----------------
// C = A (25088x768) * B^T (2304x768). BK=64, 12 K-tiles, 128KB dbuf LDS.
// Per phase: {ds_read frag cluster; issue 1 half-tile DMA (tile t+1 -> buf^1);
//   s_barrier; lgkmcnt(0)+sched_barrier; setprio(1) 16 MFMA setprio(0); s_barrier}.
// One vmcnt(0)+barrier per K-tile (drain covered by ~4 phases of compute).
// Epilogue: q (pre-scaled 0.125*log2e) / k coalesced to qkb[MP][1536];
//           v -> per-wave in-LDS 64x64 transpose (2 passes) -> coalesced vT.
__global__ __launch_bounds__(512, 2) void gemm_qkv_8ph(
    const short* __restrict__ A, const short* __restrict__ Bw,
    const float* __restrict__ bias,
    short* __restrict__ qk, short* __restrict__ vT)
{
    constexpr int K = 768;
    constexpr int KT = 12;
    // [buf][op][256*64] bf16 : 2*2*32KB = 128KB
    __shared__ __align__(16) short lds[2][2][256 * 64];

    const int tid  = threadIdx.x;
    const int lane = tid & 63;
    const int wid  = tid >> 6;      // 0..7
    const int lrow = lane & 15;
    const int lgrp = lane >> 4;
    const int wr   = wid >> 2;      // 0..1  M-half of tile
    const int wc   = wid & 3;       // 0..3  N-quarter of tile

    // XCD-bijective remap + supertile (98 m-panels = 7 groups of G=14, 9 n)
    const int nwg = gridDim.x;      // 882
    const int q8  = nwg >> 3, r8 = nwg & 7;
    const int xcd = blockIdx.x & 7, bidx = blockIdx.x >> 3;
    const int wgid = (xcd < r8 ? xcd * (q8 + 1) : r8 * (q8 + 1) + (xcd - r8) * q8) + bidx;
    constexpr int G = 14, SG = G * 9;     // 126; 882 = 7*126
    const int mg  = wgid / SG;
    const int rr_ = wgid - mg * SG;
    const int nn_ = rr_ / G;
    const int mi  = rr_ - nn_ * G;
    const int m0  = (mg * G + mi) * 256;
    const int n0  = nn_ * 256;

    f32x4 acc[8][4];
    #pragma unroll
    for (int i = 0; i < 8; ++i)
        #pragma unroll
        for (int j = 0; j < 4; ++j)
            acc[i][j] = f32x4{0.f, 0.f, 0.f, 0.f};

    // stage one half-tile (128 rows) of operand op for K-tile kt into buf.
    // 1024 chunks of 16B, 512 threads -> 2 DMA issues/thread.
    auto stage_half = [&](int kt, int buf, int op, int half) {
        const short* srcp = (op == 0) ? A : Bw;
        const int rb = (op == 0) ? m0 : n0;
        #pragma unroll
        for (int it = 0; it < 2; ++it) {
            const int c   = half * 1024 + it * 512 + tid;    // chunk in [0,2048)
            const int row = c >> 3;                           // 0..255 (incl. half)
            const int scb = ((c & 7) * 16) ^ ((row & 7) << 4); // inverse swizzle on SOURCE
            const short* g = srcp + (size_t)(rb + row) * K + kt * 64 + (scb >> 1);
            __builtin_amdgcn_global_load_lds((gas_ptr)g,
                (las_ptr)((char*)&lds[buf][op][0] + c * 16), 16, 0, 0);
        }
    };

    auto rdA = [&](int buf, int i, int ks) -> bf16x8 {
        const int r   = wr * 128 + i * 16 + lrow;
        const int byt = r * 128 + ((ks * 64 + lgrp * 16) ^ ((r & 7) << 4));
        return *reinterpret_cast<const bf16x8*>((const char*)&lds[buf][0][0] + byt);
    };
    auto rdB = [&](int buf, int j, int ks) -> bf16x8 {
        const int r   = wc * 64 + j * 16 + lrow;
        const int byt = r * 128 + ((ks * 64 + lgrp * 16) ^ ((r & 7) << 4));
        return *reinterpret_cast<const bf16x8*>((const char*)&lds[buf][1][0] + byt);
    };

    // prologue: stage tile 0 fully, drain, barrier
    stage_half(0, 0, 0, 0); stage_half(0, 0, 0, 1);
    stage_half(0, 0, 1, 0); stage_half(0, 0, 1, 1);
    asm volatile("s_waitcnt vmcnt(0)" ::: "memory");
    __builtin_amdgcn_s_barrier();

    for (int t = 0; t < KT; ++t) {
        const int cur = t & 1;
        const int nxt = cur ^ 1;
        const bool more = (t + 1 < KT);
        bf16x8 a03[2][4], a47[2][4], b01[2][2], b23[2][2];

        // ---- phase 0: rd a03 + b01 ; stage A-hi(t+1) ; MFMA acc[0..3][0..1]
        #pragma unroll
        for (int ks = 0; ks < 2; ++ks) {
            #pragma unroll
            for (int i = 0; i < 4; ++i) a03[ks][i] = rdA(cur, i, ks);
            #pragma unroll
            for (int j = 0; j < 2; ++j) b01[ks][j] = rdB(cur, j, ks);
        }
        if (more) stage_half(t + 1, nxt, 0, 0);
        __builtin_amdgcn_s_barrier();
        asm volatile("s_waitcnt lgkmcnt(0)" ::: "memory");
        __builtin_amdgcn_sched_barrier(0);
        __builtin_amdgcn_s_setprio(1);
        #pragma unroll
        for (int ks = 0; ks < 2; ++ks)
            #pragma unroll
            for (int i = 0; i < 4; ++i)
                #pragma unroll
                for (int j = 0; j < 2; ++j)
                    acc[i][j] = __builtin_amdgcn_mfma_f32_16x16x32_bf16(a03[ks][i], b01[ks][j], acc[i][j], 0, 0, 0);
        __builtin_amdgcn_s_setprio(0);
        __builtin_amdgcn_s_barrier();

        // ---- phase 1: rd b23 ; stage A-lo ; MFMA acc[0..3][2..3]
        #pragma unroll
        for (int ks = 0; ks < 2; ++ks)
            #pragma unroll
            for (int j = 0; j < 2; ++j) b23[ks][j] = rdB(cur, 2 + j, ks);
        if (more) stage_half(t + 1, nxt, 0, 1);
        __builtin_amdgcn_s_barrier();
        asm volatile("s_waitcnt lgkmcnt(0)" ::: "memory");
        __builtin_amdgcn_sched_barrier(0);
        __builtin_amdgcn_s_setprio(1);
        #pragma unroll
        for (int ks = 0; ks < 2; ++ks)
            #pragma unroll
            for (int i = 0; i < 4; ++i)
                #pragma unroll
                for (int j = 0; j < 2; ++j)
                    acc[i][2 + j] = __builtin_amdgcn_mfma_f32_16x16x32_bf16(a03[ks][i], b23[ks][j], acc[i][2 + j], 0, 0, 0);
        __builtin_amdgcn_s_setprio(0);
        __builtin_amdgcn_s_barrier();

        // ---- phase 2: rd a47 ; stage B-hi ; MFMA acc[4..7][2..3]
        #pragma unroll
        for (int ks = 0; ks < 2; ++ks)
            #pragma unroll
            for (int i = 0; i < 4; ++i) a47[ks][i] = rdA(cur, 4 + i, ks);
        if (more) stage_half(t + 1, nxt, 1, 0);
        __builtin_amdgcn_s_barrier();
        asm volatile("s_waitcnt lgkmcnt(0)" ::: "memory");
        __builtin_amdgcn_sched_barrier(0);
        __builtin_amdgcn_s_setprio(1);
        #pragma unroll
        for (int ks = 0; ks < 2; ++ks)
            #pragma unroll
            for (int i = 0; i < 4; ++i)
                #pragma unroll
                for (int j = 0; j < 2; ++j)
                    acc[4 + i][2 + j] = __builtin_amdgcn_mfma_f32_16x16x32_bf16(a47[ks][i], b23[ks][j], acc[4 + i][2 + j], 0, 0, 0);
        __builtin_amdgcn_s_setprio(0);
        __builtin_amdgcn_s_barrier();

        // ---- phase 3: re-rd b01 ; stage B-lo ; MFMA acc[4..7][0..1]
        #pragma unroll
        for (int ks = 0; ks < 2; ++ks)
            #pragma unroll
            for (int j = 0; j < 2; ++j) b01[ks][j] = rdB(cur, j, ks);
        if (more) stage_half(t + 1, nxt, 1, 1);
        __builtin_amdgcn_s_barrier();
        asm volatile("s_waitcnt lgkmcnt(0)" ::: "memory");
        __builtin_amdgcn_sched_barrier(0);
        __builtin_amdgcn_s_setprio(1);
        #pragma unroll
        for (int ks = 0; ks < 2; ++ks)
            #pragma unroll
            for (int i = 0; i < 4; ++i)
                #pragma unroll
                for (int j = 0; j < 2; ++j)
                    acc[4 + i][j] = __builtin_amdgcn_mfma_f32_16x16x32_bf16(a47[ks][i], b01[ks][j], acc[4 + i][j], 0, 0, 0);
        __builtin_amdgcn_s_setprio(0);

        // ---- K-tile end: next tile must be fully landed before ph0 ds_reads
        __builtin_amdgcn_sched_barrier(0);
        asm volatile("s_waitcnt vmcnt(0)" ::: "memory");
        __builtin_amdgcn_s_barrier();
    }

    // ---------------- epilogue ----------------
    const int mb = m0 + wr * 128;
    const int nb = n0 + wc * 64;
    if (n0 < 1536) {
        // q/k: coalesced bf16 store into qkb [MP][1536]
        #pragma unroll
        for (int j = 0; j < 4; ++j) {
            const int c  = nb + j * 16 + lrow;
            const float sc = (c < 768) ? 0.18033688011116f : 1.0f;  // 0.125*log2(e) on q
            const float bv = bias[c];
            #pragma unroll
            for (int i = 0; i < 8; ++i) {
                #pragma unroll
                for (int r = 0; r < 4; ++r) {
                    const int m = mb + i * 16 + lgrp * 4 + r;
                    qk[(size_t)m * 1536 + c] = f2bf((acc[i][j][r] + bv) * sc);
                }
            }
        }
    } else {
        // v: per-wave 64x64 in-LDS transpose (2 passes of 64 rows), coalesced vT store
        const int h = (nb - 1536) >> 6;
        short* lw = (short*)&lds[0][0][0] + wid * (64 * 80);   // 10KB/wave in the pool
        #pragma unroll
        for (int pass = 0; pass < 2; ++pass) {
            if (pass) {  // pass-0 reads retired before overwrite
                asm volatile("s_waitcnt lgkmcnt(0)" ::: "memory");
                __builtin_amdgcn_sched_barrier(0);
            }
            #pragma unroll
            for (int j = 0; j < 4; ++j) {
                const int dloc = j * 16 + lrow;
                const float bv = bias[nb + j * 16 + lrow];
                #pragma unroll
                for (int ii = 0; ii < 4; ++ii)
                    #pragma unroll
                    for (int r = 0; r < 4; ++r)
                        lw[dloc * 80 + ii * 16 + lgrp * 4 + r] = f2bf(acc[pass * 4 + ii][j][r] + bv);
            }
            asm volatile("s_waitcnt lgkmcnt(0)" ::: "memory");
            __builtin_amdgcn_sched_barrier(0);
            #pragma unroll
            for (int w = 0; w < 8; ++w) {
                const int d    = w * 8 + (lane >> 3);
                const int nloc = (lane & 7) * 8;
                const bf16x8 val = *reinterpret_cast<const bf16x8*>(lw + d * 80 + nloc);
                const int mchunk = mb + pass * 64 + nloc;      // mult of 8; 392%8==0
                const int b  = mchunk / 392;
                const int nn = mchunk - b * 392;
                short* dst = vT + ((size_t)(b * 12 + h) * 64 + d) * 392 + nn;
                *reinterpret_cast<bf16x8*>(dst) = val;
            }
        }
    }
}

// ---------------- proj GEMM (unchanged r9 structure, MODE-1 path) ----------
__global__ __launch_bounds__(256) void gemm_proj(
    const short* __restrict__ A, const short* __restrict__ Bw,
    const float* __restrict__ bias, float* __restrict__ fo, int NB)
{
    constexpr int K = 768;
    constexpr int KT = 12;
    __shared__ __align__(16) short ldsraw[2 * 128 * 64 * 2];
    short* ldsA = ldsraw;
    short* ldsB = ldsraw + 2 * 128 * 64;

    const int tid  = threadIdx.x;
    const int lane = tid & 63;
    const int wid  = tid >> 6;
    const int lrow = lane & 15;
    const int lgrp = lane >> 4;
    const int wr   = wid >> 1;
    const int wc   = wid & 1;

    const int nwg = gridDim.x;
    const int q8  = nwg >> 3, r8 = nwg & 7;
    const int xcd = blockIdx.x & 7, bidx = blockIdx.x >> 3;
    const int wgid = (xcd < r8 ? xcd * (q8 + 1) : r8 * (q8 + 1) + (xcd - r8) * q8) + bidx;
    const int m0 = (wgid / NB) * 128;
    const int n0 = (wgid % NB) * 128;

    f32x4 acc[4][4];
    #pragma unroll
    for (int i = 0; i < 4; ++i)
        #pragma unroll
        for (int j = 0; j < 4; ++j)
            acc[i][j] = f32x4{0.f, 0.f, 0.f, 0.f};

    auto stage = [&](int kt, int buf) {
        #pragma unroll
        for (int it = 0; it < 4; ++it) {
            const int c   = it * 256 + wid * 64 + lane;
            const int row = c >> 3;
            const int scb = ((c & 7) * 16) ^ ((row & 7) << 4);
            const short* ga = A  + (size_t)(m0 + row) * K + kt * 64 + (scb >> 1);
            const short* gb = Bw + (size_t)(n0 + row) * K + kt * 64 + (scb >> 1);
            __builtin_amdgcn_global_load_lds((gas_ptr)ga, (las_ptr)((char*)(ldsA + buf * 128 * 64) + c * 16), 16, 0, 0);
            __builtin_amdgcn_global_load_lds((gas_ptr)gb, (las_ptr)((char*)(ldsB + buf * 128 * 64) + c * 16), 16, 0, 0);
        }
    };

    stage(0, 0);

    for (int kt = 0; kt < KT; ++kt) {
        const int cur = kt & 1;
        if (kt + 1 < KT) {
            stage(kt + 1, cur ^ 1);
            asm volatile("s_waitcnt vmcnt(8)" ::: "memory");
        } else {
            asm volatile("s_waitcnt vmcnt(0)" ::: "memory");
        }
        __builtin_amdgcn_s_barrier();
        __builtin_amdgcn_sched_barrier(0);

        #pragma unroll
        for (int ks = 0; ks < 2; ++ks) {
            bf16x8 af[4], bfv[4];
            #pragma unroll
            for (int i = 0; i < 4; ++i) {
                const int r   = wr * 64 + i * 16 + lrow;
                const int byt = r * 128 + ((ks * 64 + lgrp * 16) ^ ((r & 7) << 4));
                af[i] = *reinterpret_cast<const bf16x8*>((const char*)(ldsA + cur * 128 * 64) + byt);
            }
            #pragma unroll
            for (int j = 0; j < 4; ++j) {
                const int r   = wc * 64 + j * 16 + lrow;
                const int byt = r * 128 + ((ks * 64 + lgrp * 16) ^ ((r & 7) << 4));
                bfv[j] = *reinterpret_cast<const bf16x8*>((const char*)(ldsB + cur * 128 * 64) + byt);
            }
            #pragma unroll
            for (int i = 0; i < 4; ++i)
                #pragma unroll
                for (int j = 0; j < 4; ++j)
                    acc[i][j] = __builtin_amdgcn_mfma_f32_16x16x32_bf16(af[i], bfv[j], acc[i][j], 0, 0, 0);
        }

        __builtin_amdgcn_sched_barrier(0);
        __builtin_amdgcn_s_barrier();
    }

    const int mb = m0 + wr * 64;
    const int nb = n0 + wc * 64;
    #pragma unroll
    for (int i = 0; i < 4; ++i) {
        #pragma unroll
        for (int r = 0; r < 4; ++r) {
            const int m = mb + i * 16 + lgrp * 4 + r;
            #pragma unroll
            for (int j = 0; j < 4; ++j) {
                const int c = nb + j * 16 + lrow;
                fo[(size_t)m * 768 + c] = acc[i][j][r] + bias[c];
            }
        }
    }
}

// ---------------- flash attention (unchanged from round 9) ----------------
constexpr int PSTRB = 256;   // P row stride BYTES (128 shorts), XOR-swizzled

template<int NT, bool VLDS>
static __device__ __forceinline__ void attn_chunk_lds(
    int kbeg, int k_len,
    const short* __restrict__ klds, const short* __restrict__ vlds,
    const short* __restrict__ vglob,
    const bf16x8 (&qf)[2], char* __restrict__ my,
    int lrow, int lgrp,
    float (&rs)[4], f32x4 (&oacc)[4])
{
    f32x4 sacc[NT];
    #pragma unroll
    for (int t = 0; t < NT; ++t) sacc[t] = f32x4{0.f, 0.f, 0.f, 0.f};

    #pragma unroll
    for (int t = 0; t < NT; ++t) {
        const int kl   = t * 16 + lrow;
        const int byt0 = kl * 128 + ((lgrp * 16) ^ ((kl & 7) << 4));
        const int byt1 = kl * 128 + ((64 + lgrp * 16) ^ ((kl & 7) << 4));
        const bf16x8 k0 = *reinterpret_cast<const bf16x8*>((const char*)klds + byt0);
        const bf16x8 k1 = *reinterpret_cast<const bf16x8*>((const char*)klds + byt1);
        sacc[t] = __builtin_amdgcn_mfma_f32_16x16x32_bf16(qf[0], k0, sacc[t], 0, 0, 0);
        sacc[t] = __builtin_amdgcn_mfma_f32_16x16x32_bf16(qf[1], k1, sacc[t], 0, 0, 0);
    }
    #pragma unroll
    for (int t = 0; t < NT; ++t) {
        const bool bad = (kbeg + t * 16 + lrow >= k_len);
        #pragma unroll
        for (int r = 0; r < 4; ++r) {
            const float p = bad ? 0.f : exp2f(sacc[t][r]);
            rs[r] += p;
            const int row = lgrp * 4 + r;
            const int byt = row * PSTRB + ((t * 32 + lrow * 2) ^ ((row & 7) << 4));
            *reinterpret_cast<short*>(my + byt) = f2bf(p);
        }
    }

    #pragma unroll
    for (int ks = 0; ks < NT / 2; ++ks) {
        const bf16x8 pf = *reinterpret_cast<const bf16x8*>(
            my + lrow * PSTRB + ((ks * 64 + lgrp * 16) ^ ((lrow & 7) << 4)));
        #pragma unroll
        for (int dt = 0; dt < 4; ++dt) {
            const int d = dt * 16 + lrow;
            const bf16x8 vf = VLDS
                ? *reinterpret_cast<const bf16x8*>((const char*)vlds + d * 256 + ((ks * 64 + lgrp * 16) ^ ((d & 7) << 4)))
                : *reinterpret_cast<const bf16x8*>(vglob + (size_t)d * 392 + ks * 32 + lgrp * 8);
            oacc[dt] = __builtin_amdgcn_mfma_f32_16x16x32_bf16(pf, vf, oacc[dt], 0, 0, 0);
        }
    }
}

__global__ __launch_bounds__(256, 2) void attn_flash(
    const short* __restrict__ qkb, const short* __restrict__ vT,
    short* __restrict__ ao)
{
    __shared__ __align__(16) short klds[2][128 * 64];
    __shared__ __align__(16) short vlds[2][64 * 128];
    __shared__ __align__(16) char  plds[4][16 * PSTRB];

    const int tid  = threadIdx.x;
    const int lane = tid & 63;
    const int wid  = tid >> 6;
    const int lrow = lane & 15;
    const int lgrp = lane >> 4;

    const int blk = blockIdx.x;
    const int xcd = blk & 7;
    const int i7  = blk >> 3;
    const int bh  = xcd * 96 + i7 / 7;
    const int bx  = i7 % 7;

    int q_start, qend, k_len, nfull;
    bool tail;
    if (bx < 2) { q_start = bx * 64;             qend = 128; k_len = 128; nfull = 1; tail = false; }
    else        { q_start = 128 + (bx - 2) * 64; qend = 388; k_len = 388; nfull = 3; tail = true;  }

    const int q0 = q_start + wid * 16;

    const int b = bh / 12, h = bh - b * 12;
    const short* qbase = qkb + (size_t)b * 392 * 1536 + h * 64;
    const short* kbase = qbase + 768;
    const short* vbase = vT + (size_t)bh * 64 * 392;

    int qrow = q0 + lrow; if (qrow >= qend) qrow = qend - 1;
    bf16x8 qf[2];
    #pragma unroll
    for (int ks = 0; ks < 2; ++ks)
        qf[ks] = *reinterpret_cast<const bf16x8*>(qbase + (size_t)qrow * 1536 + ks * 32 + lgrp * 8);

    float rs[4] = {0.f, 0.f, 0.f, 0.f};
    f32x4 oacc[4];
    #pragma unroll
    for (int dt = 0; dt < 4; ++dt) oacc[dt] = f32x4{0.f, 0.f, 0.f, 0.f};

    char* my = &plds[wid][0];

    auto stage_full = [&](int ch, int buf) {
        const int kbeg = ch * 128;
        #pragma unroll
        for (int it = 0; it < 4; ++it) {
            const int c = it * 256 + tid;
            const int krow = c >> 3;
            const int kscb = ((c & 7) * 16) ^ ((krow & 7) << 4);
            const short* gk = kbase + (size_t)(kbeg + krow) * 1536 + (kscb >> 1);
            __builtin_amdgcn_global_load_lds((gas_ptr)gk, (las_ptr)((char*)&klds[buf][0] + c * 16), 16, 0, 0);
            const int vrow = c >> 4;
            const int vscb = ((c & 15) * 16) ^ ((vrow & 7) << 4);
            const short* gv = vbase + (size_t)vrow * 392 + kbeg + (vscb >> 1);
            __builtin_amdgcn_global_load_lds((gas_ptr)gv, (las_ptr)((char*)&vlds[buf][0] + c * 16), 16, 0, 0);
        }
    };

    stage_full(0, 0);

    for (int ch = 0; ch < nfull; ++ch) {
        const int cur = ch & 1;
        if (ch + 1 < nfull) {
            stage_full(ch + 1, cur ^ 1);
            asm volatile("s_waitcnt vmcnt(8)" ::: "memory");
        } else {
            asm volatile("s_waitcnt vmcnt(0)" ::: "memory");
        }
        __builtin_amdgcn_s_barrier();
        __builtin_amdgcn_sched_barrier(0);

        attn_chunk_lds<8, true>(ch * 128, k_len, &klds[cur][0], &vlds[cur][0],
                                nullptr, qf, my, lrow, lgrp, rs, oacc);

        __builtin_amdgcn_sched_barrier(0);
        __builtin_amdgcn_s_barrier();
    }

    if (tail) {
        {
            const int c = tid;
            const int krow = c >> 3;
            const int kscb = ((c & 7) * 16) ^ ((krow & 7) << 4);
            int g = 384 + krow; if (g > 391) g = 391;
            const short* gk = kbase + (size_t)g * 1536 + (kscb >> 1);
            __builtin_amdgcn_global_load_lds((gas_ptr)gk, (las_ptr)((char*)&klds[0][0] + c * 16), 16, 0, 0);
        }
        asm volatile("s_waitcnt vmcnt(0)" ::: "memory");
        __builtin_amdgcn_s_barrier();
        __builtin_amdgcn_sched_barrier(0);

        attn_chunk_lds<2, false>(384, k_len, &klds[0][0], nullptr, vbase + 384,
                                 qf, my, lrow, lgrp, rs, oacc);
    }

    #pragma unroll
    for (int msk = 1; msk < 16; msk <<= 1)
        #pragma unroll
        for (int r = 0; r < 4; ++r) rs[r] += __shfl_xor(rs[r], msk, 64);

    float inv[4];
    #pragma unroll
    for (int r = 0; r < 4; ++r) inv[r] = 1.0f / rs[r];
    #pragma unroll
    for (int r = 0; r < 4; ++r) {
        const int qn = q0 + lgrp * 4 + r;
        if (qn < qend) {
            #pragma unroll
            for (int dt = 0; dt < 4; ++dt)
                ao[((size_t)b * 388 + qn) * 768 + h * 64 + dt * 16 + lrow] =
                    f2bf(oacc[dt][r] * inv[r]);
        }
    }
}

extern "C" void kernel_launch(void* const* d_in, const int* in_sizes, int n_in,
                              void* d_out, int out_size, void* d_ws, size_t ws_size,
                              hipStream_t stream) {
    (void)in_sizes; (void)n_in; (void)out_size; (void)ws_size;
    const float* x      = (const float*)d_in[0];
    const float* qkv_w  = (const float*)d_in[1];
    const float* qkv_b  = (const float*)d_in[2];
    const float* proj_w = (const float*)d_in[3];
    const float* proj_b = (const float*)d_in[4];
    float* out = (float*)d_out;

    // ---- workspace layout (bytes) ----
    char* ws = (char*)d_ws;
    short* xb   = (short*)(ws);                       // [25088][768] bf16 (padded x)
    short* attn = (short*)(ws);                       //   alias: xb dead after QKV GEMM
    short* qkb  = (short*)(ws + 38535168);            // [25088][1536] bf16 (q|k)
    short* vTb  = (short*)(ws + 115605504);           // [768][64][392] bf16
    short* qwb  = (short*)(ws + 154140672);           // 2304x768 bf16
    short* pwb  = (short*)(ws + 157679616);           // 768x768 bf16

    cvt_x_pad  <<<2048, 256, 0, stream>>>(x, xb);
    cvt_f32_bf16<<<512,  256, 0, stream>>>(qkv_w,  qwb, 2304 * 768 / 4);
    cvt_f32_bf16<<<256,  256, 0, stream>>>(proj_w, pwb, 768 * 768 / 4);

    // QKV GEMM: M'=25088 (98x256), N=2304 (9x256), 8-wave 4-phase pipeline
    gemm_qkv_8ph<<<dim3(98 * 9), 512, 0, stream>>>(xb, qwb, qkv_b, qkb, vTb);

    attn_flash<<<dim3(5376), 256, 0, stream>>>(qkb, vTb, attn);

    // proj GEMM: M=24832 (194x128), N=768 (6x128)
    gemm_proj<<<dim3(194 * 6), 256, 0, stream>>>(attn, pwb, proj_b, out, 6);
}